// Round 6
// baseline (246.990 us; speedup 1.0000x reference)
//
#include <hip/hip_runtime.h>

#define D 64
#define BSH2 8                   // 256 nodes per coarse bucket
#define NPB 256                  // nodes per bucket (1<<BSH2)
#define NB2_MAX 1024             // max coarse buckets (N <= 256k)
#define PCHUNK 2048              // edges per partition/hist block

// ---------------- utility ----------------

__global__ void zero_i32(int* __restrict__ p, int n) {
    int i = blockIdx.x * blockDim.x + threadIdx.x;
    if (i < n) p[i] = 0;
}

__global__ void zero_f32(float* __restrict__ p, long n) {
    long i = (long)blockIdx.x * blockDim.x + threadIdx.x;
    long stride = (long)gridDim.x * blockDim.x;
    for (; i < n; i += stride) p[i] = 0.0f;
}

// ---------------- build pipeline ----------------

// per-block LDS histogram of coarse buckets; flush to padded global counters
__global__ __launch_bounds__(256) void coarse_hist(const int* __restrict__ dst,
                                                   int* __restrict__ bcntp,  // stride 16
                                                   int E, int NB2) {
    __shared__ int lh[NB2_MAX];
    int tid = threadIdx.x;
    int c0 = blockIdx.x * PCHUNK;
    int c1 = c0 + PCHUNK; if (c1 > E) c1 = E;
    for (int i = tid; i < NB2; i += 256) lh[i] = 0;
    __syncthreads();
    // vectorized main body
    for (int e = c0 + tid * 4; e + 4 <= c1; e += 1024) {
        int4 d4 = *(const int4*)(dst + e);
        atomicAdd(&lh[d4.x >> BSH2], 1);
        atomicAdd(&lh[d4.y >> BSH2], 1);
        atomicAdd(&lh[d4.z >> BSH2], 1);
        atomicAdd(&lh[d4.w >> BSH2], 1);
    }
    // scalar tail (last <4 edges of a short final chunk)
    int tail = c0 + ((c1 - c0) & ~3);
    for (int e = tail + tid; e < c1; e += 256)
        atomicAdd(&lh[dst[e] >> BSH2], 1);
    __syncthreads();
    for (int i = tid; i < NB2; i += 256) {
        int c = lh[i];
        if (c) atomicAdd(&bcntp[i << 4], c);
    }
}

// one block: exclusive scan of NB2 (<=1024) padded counts -> off, and tails fillp
__global__ __launch_bounds__(256) void scan_coarse(const int* __restrict__ bcntp,
                                                   int* __restrict__ off,
                                                   int* __restrict__ fillp,
                                                   int NB2, int E) {
    __shared__ int s[256];
    int tid = threadIdx.x;
    int v[4]; int sum = 0;
    for (int j = 0; j < 4; j++) {
        int i = tid * 4 + j;
        int c = (i < NB2) ? bcntp[i << 4] : 0;
        v[j] = sum; sum += c;
    }
    s[tid] = sum;
    __syncthreads();
    for (int o = 1; o < 256; o <<= 1) {
        int t = (tid >= o) ? s[tid - o] : 0;
        __syncthreads();
        s[tid] += t;
        __syncthreads();
    }
    int excl = s[tid] - sum;
    for (int j = 0; j < 4; j++) {
        int i = tid * 4 + j;
        if (i < NB2) { int val = excl + v[j]; off[i] = val; fillp[i << 4] = val; }
    }
    if (tid == 0) off[NB2] = E;
}

// each block: LDS hist of its chunk, one padded atomic per bucket to reserve a
// contiguous range, then place edges at lbase[k]++.
// packed = src | (dst & 255) << 20   (requires N <= 2^20)
__global__ __launch_bounds__(256) void partition_kernel(const int* __restrict__ src,
                                                        const int* __restrict__ dst,
                                                        int* __restrict__ fillp, // stride 16
                                                        int* __restrict__ packed,
                                                        int E, int NB2) {
    __shared__ int lhist[NB2_MAX];
    __shared__ int lbase[NB2_MAX];
    int tid = threadIdx.x;
    int c0 = blockIdx.x * PCHUNK;
    int c1 = c0 + PCHUNK; if (c1 > E) c1 = E;
    for (int i = tid; i < NB2; i += 256) lhist[i] = 0;
    __syncthreads();
    for (int e = c0 + tid * 4; e + 4 <= c1; e += 1024) {
        int4 d4 = *(const int4*)(dst + e);
        atomicAdd(&lhist[d4.x >> BSH2], 1);
        atomicAdd(&lhist[d4.y >> BSH2], 1);
        atomicAdd(&lhist[d4.z >> BSH2], 1);
        atomicAdd(&lhist[d4.w >> BSH2], 1);
    }
    int tail = c0 + ((c1 - c0) & ~3);
    for (int e = tail + tid; e < c1; e += 256)
        atomicAdd(&lhist[dst[e] >> BSH2], 1);
    __syncthreads();
    for (int i = tid; i < NB2; i += 256) {
        int c = lhist[i];
        lbase[i] = c ? atomicAdd(&fillp[i << 4], c) : 0;
    }
    __syncthreads();
    for (int e = c0 + tid * 4; e + 4 <= c1; e += 1024) {
        int4 d4 = *(const int4*)(dst + e);
        int4 s4 = *(const int4*)(src + e);
        int k, pos;
        k = d4.x >> BSH2; pos = atomicAdd(&lbase[k], 1);
        packed[pos] = s4.x | ((d4.x & (NPB - 1)) << 20);
        k = d4.y >> BSH2; pos = atomicAdd(&lbase[k], 1);
        packed[pos] = s4.y | ((d4.y & (NPB - 1)) << 20);
        k = d4.z >> BSH2; pos = atomicAdd(&lbase[k], 1);
        packed[pos] = s4.z | ((d4.z & (NPB - 1)) << 20);
        k = d4.w >> BSH2; pos = atomicAdd(&lbase[k], 1);
        packed[pos] = s4.w | ((d4.w & (NPB - 1)) << 20);
    }
    for (int e = tail + tid; e < c1; e += 256) {
        int d = dst[e];
        int k = d >> BSH2;
        int pos = atomicAdd(&lbase[k], 1);
        packed[pos] = src[e] | ((d & (NPB - 1)) << 20);
    }
}

// one block per coarse bucket: per-node counts (LDS) -> in-block scan gives
// row_ptr + deg (fused norm/norm2), second sweep places csr entries.
__global__ __launch_bounds__(256) void bucket_csr(const int* __restrict__ packed,
                                                  const int* __restrict__ off,
                                                  int* __restrict__ row_ptr,
                                                  float* __restrict__ norm,
                                                  float* __restrict__ norm2,
                                                  int* __restrict__ csr,
                                                  int N, int NB2) {
    __shared__ int cnt[NPB];
    __shared__ int pre[NPB];
    int b = blockIdx.x;
    int tid = threadIdx.x;
    cnt[tid] = 0;
    __syncthreads();
    int beg = off[b], end = off[b + 1];
    for (int e = beg + tid; e < end; e += 256)
        atomicAdd(&cnt[(packed[e] >> 20) & (NPB - 1)], 1);
    __syncthreads();
    int v = cnt[tid];
    pre[tid] = v;
    __syncthreads();
    for (int o = 1; o < 256; o <<= 1) {
        int t = (tid >= o) ? pre[tid - o] : 0;
        __syncthreads();
        pre[tid] += t;
        __syncthreads();
    }
    int excl = pre[tid] - v;
    int node = (b << BSH2) + tid;
    if (node < N) {
        row_ptr[node] = beg + excl;
        float df = (float)v; df = df < 1.0f ? 1.0f : df;
        float r = rsqrtf(df);
        norm[node] = r;
        norm2[node] = r * r;
    }
    if (b == NB2 - 1 && tid == 0) row_ptr[N] = end;   // == E
    // reuse cnt as running placement cursor
    cnt[tid] = beg + excl;
    __syncthreads();
    for (int e = beg + tid; e < end; e += 256) {
        int p = packed[e];
        int pos = atomicAdd(&cnt[(p >> 20) & (NPB - 1)], 1);
        csr[pos] = p & 0xFFFFF;
    }
}

// ---------------- gather: one wave per node, unroll-2 for MLP ----------------

template <bool HS>
__global__ __launch_bounds__(256) void gather_csr(const float* __restrict__ x,
                                                  const float* __restrict__ scale,
                                                  const int* __restrict__ row_ptr,
                                                  const int* __restrict__ csr,
                                                  const float* __restrict__ post,
                                                  float* __restrict__ out, int N) {
    int w = blockIdx.x * 4 + (threadIdx.x >> 6);
    if (w >= N) return;
    int lane = threadIdx.x & 63;
    int g = lane >> 4;
    int sub = lane & 15;
    int beg = row_ptr[w], end = row_ptr[w + 1];
    const float4* x4 = (const float4*)x;
    float ax = 0.f, ay = 0.f, az = 0.f, aw = 0.f;
    int e = beg + g;
    // unrolled by 2: keep 2 rows (+2 idx, +2 scale) in flight per 16-lane group
    for (; e + 4 < end; e += 8) {
        int s0 = csr[e];
        int s1 = csr[e + 4];
        float c0 = HS ? scale[s0] : 1.0f;
        float c1 = HS ? scale[s1] : 1.0f;
        float4 v0 = x4[s0 * (D / 4) + sub];
        float4 v1 = x4[s1 * (D / 4) + sub];
        ax += v0.x * c0; ay += v0.y * c0; az += v0.z * c0; aw += v0.w * c0;
        ax += v1.x * c1; ay += v1.y * c1; az += v1.z * c1; aw += v1.w * c1;
    }
    if (e < end) {
        int s0 = csr[e];
        float c0 = HS ? scale[s0] : 1.0f;
        float4 v0 = x4[s0 * (D / 4) + sub];
        ax += v0.x * c0; ay += v0.y * c0; az += v0.z * c0; aw += v0.w * c0;
    }
    ax += __shfl_xor(ax, 16, 64); ay += __shfl_xor(ay, 16, 64);
    az += __shfl_xor(az, 16, 64); aw += __shfl_xor(aw, 16, 64);
    ax += __shfl_xor(ax, 32, 64); ay += __shfl_xor(ay, 32, 64);
    az += __shfl_xor(az, 32, 64); aw += __shfl_xor(aw, 32, 64);
    if (g == 0) {
        float pn = post[w];
        float4 r; r.x = ax * pn; r.y = ay * pn; r.z = az * pn; r.w = aw * pn;
        ((float4*)(out + (long)w * D))[sub] = r;
    }
}

// ---------------- fallback (atomic push, round-1) ----------------

__global__ void deg_kernel_f(const int* __restrict__ dst, float* __restrict__ deg, int E) {
    int e = blockIdx.x * blockDim.x + threadIdx.x;
    if (e < E) unsafeAtomicAdd(&deg[dst[e]], 1.0f);
}

__global__ void norm_kernel_f(float* __restrict__ deg_norm, float* __restrict__ norm2, int N) {
    int i = blockIdx.x * blockDim.x + threadIdx.x;
    if (i < N) {
        float d = deg_norm[i];
        d = d < 1.0f ? 1.0f : d;
        float r = rsqrtf(d);
        deg_norm[i] = r;
        norm2[i] = r * r;
    }
}

__global__ void scatter_kernel(const float* __restrict__ x,
                               const float* __restrict__ scale,
                               const int* __restrict__ src,
                               const int* __restrict__ dst,
                               float* __restrict__ out, int E) {
    long idx = (long)blockIdx.x * blockDim.x + threadIdx.x;
    int e = (int)(idx >> 6);
    int lane = (int)(idx & 63);
    if (e < E) {
        int s = src[e];
        int d0 = dst[e];
        float v = x[(long)s * D + lane] * scale[s];
        unsafeAtomicAdd(&out[(long)d0 * D + lane], v);
    }
}

__global__ void scale_kernel(float* __restrict__ out, const float* __restrict__ norm, long n) {
    long i = (long)blockIdx.x * blockDim.x + threadIdx.x;
    if (i < n) out[i] *= norm[i >> 6];
}

// ---------------- launch ----------------

extern "C" void kernel_launch(void* const* d_in, const int* in_sizes, int n_in,
                              void* d_out, int out_size, void* d_ws, size_t ws_size,
                              hipStream_t stream) {
    const float* feat = (const float*)d_in[0];
    const int*   src  = (const int*)d_in[1];
    const int*   dst  = (const int*)d_in[2];
    float* out = (float*)d_out;

    const int N = in_sizes[0] / D;   // 100000
    const int E = in_sizes[1];       // 1200000
    const long ND = (long)N * D;
    const int NB2 = (N + NPB - 1) >> BSH2;   // coarse buckets

    // ws layout (4B elems):
    //   bcntp[NB2_MAX*16] | fillp[NB2_MAX*16] | off[NB2+1] | row_ptr[N+1] |
    //   csr[E] | norm[N] | norm2[N] | pad | buf1[max(ND,E)]
    //   (packed[E] aliases buf1 -- dead before gather1 writes buf1)
    long o_bcntp = 0;
    long o_fillp = o_bcntp + NB2_MAX * 16;
    long o_off   = o_fillp + NB2_MAX * 16;
    long o_rowp  = o_off + NB2 + 1;
    long o_csr   = o_rowp + N + 1;
    long o_norm  = o_csr + E;
    long o_norm2 = o_norm + N;
    long o_buf1  = (o_norm2 + N + 3) & ~3L;   // 16B align
    long buf1_len = (ND > (long)E) ? ND : (long)E;
    size_t need = (size_t)(o_buf1 + buf1_len) * 4;

    if (ws_size >= need && N <= (1 << 20) && NB2 <= NB2_MAX) {
        int*   bi = (int*)d_ws;
        float* bf = (float*)d_ws;
        int* bcntp   = bi + o_bcntp;
        int* fillp   = bi + o_fillp;
        int* off     = bi + o_off;
        int* row_ptr = bi + o_rowp;
        int* csr     = bi + o_csr;
        float* norm  = bf + o_norm;
        float* norm2 = bf + o_norm2;
        float* buf1  = bf + o_buf1;
        int* packed  = (int*)buf1;

        int pblocks = (E + PCHUNK - 1) / PCHUNK;

        zero_i32<<<(NB2_MAX * 16 + 255) / 256, 256, 0, stream>>>(bcntp, NB2_MAX * 16);
        coarse_hist<<<pblocks, 256, 0, stream>>>(dst, bcntp, E, NB2);
        scan_coarse<<<1, 256, 0, stream>>>(bcntp, off, fillp, NB2, E);
        partition_kernel<<<pblocks, 256, 0, stream>>>(src, dst, fillp, packed, E, NB2);
        bucket_csr<<<NB2, 256, 0, stream>>>(packed, off, row_ptr, norm, norm2, csr, N, NB2);

        int gblocks = (N + 3) / 4;   // 4 waves (nodes) per block
        // hop 1: buf1 = norm2 ⊙ S(norm ⊙ feat)
        gather_csr<true><<<gblocks, 256, 0, stream>>>(feat, norm, row_ptr, csr, norm2, buf1, N);
        // hop 2: out = norm ⊙ S(buf1)
        gather_csr<false><<<gblocks, 256, 0, stream>>>(buf1, nullptr, row_ptr, csr, norm, out, N);
    } else {
        // fallback: atomic push mode
        float* norm  = (float*)d_ws;
        float* norm2 = norm + N;
        float* buf1  = norm2 + N;

        long nz = 2L * N + ND;
        zero_f32<<<(int)((nz + 255) / 256), 256, 0, stream>>>((float*)d_ws, nz);
        zero_f32<<<(int)((ND + 255) / 256), 256, 0, stream>>>(out, ND);
        deg_kernel_f<<<(E + 255) / 256, 256, 0, stream>>>(dst, norm, E);
        norm_kernel_f<<<(N + 255) / 256, 256, 0, stream>>>(norm, norm2, N);
        long work = (long)E * D;
        int blocks = (int)((work + 255) / 256);
        scatter_kernel<<<blocks, 256, 0, stream>>>(feat, norm, src, dst, buf1, E);
        scatter_kernel<<<blocks, 256, 0, stream>>>(buf1, norm2, src, dst, out, E);
        scale_kernel<<<(int)((ND + 255) / 256), 256, 0, stream>>>(out, norm, ND);
    }
}

// Round 7
// 233.055 us; speedup vs baseline: 1.0598x; 1.0598x over previous
//
#include <hip/hip_runtime.h>

#define D 64
#define BSH2 9                   // 512 nodes per coarse bucket
#define NPB 512                  // nodes per bucket
#define NB2_MAX 256              // max buckets (N <= 131072)
#define PCHUNK 4096              // edges per partition block
#define CAPP 12288               // packed region capacity per bucket (incl. pad)
#define CAP2 7168                // csr region capacity per bucket (real edges)

// ---------------- utility ----------------

__global__ void zero_f32(float* __restrict__ p, long n) {
    long i = (long)blockIdx.x * blockDim.x + threadIdx.x;
    long stride = (long)gridDim.x * blockDim.x;
    for (; i < n; i += stride) p[i] = 0.0f;
}

__global__ void init_cursors(int* __restrict__ gcur, int NB2) {
    int i = blockIdx.x * blockDim.x + threadIdx.x;
    if (i < NB2) gcur[i << 4] = i * CAPP;
}

// ---------------- build: single-pass partition ----------------
// Each block: LDS-histogram its chunk -> in-block scan -> sort chunk into LDS
// by bucket -> flush each bucket-run with a 16-edge-aligned global reservation
// and coalesced stores (sentinel -1 pads the tail). Every 64B line of packed[]
// is written by exactly one block: no cross-XCD line ping-pong.
// packed = src | (dst & 511) << 20   (requires N <= 2^20)
__global__ __launch_bounds__(256) void partition_direct(const int* __restrict__ src,
                                                        const int* __restrict__ dst,
                                                        int* __restrict__ gcur,  // stride 16
                                                        int* __restrict__ packed,
                                                        int E, int NB2) {
    __shared__ int staged[PCHUNK];     // 16 KB sorted chunk
    __shared__ int lhist[NB2_MAX];
    __shared__ int lbase[NB2_MAX];
    __shared__ int lcur[NB2_MAX];
    int tid = threadIdx.x;
    int c0 = blockIdx.x * PCHUNK;
    int c1 = c0 + PCHUNK; if (c1 > E) c1 = E;

    if (tid < NB2_MAX) lhist[tid] = 0;
    __syncthreads();

    // 1: histogram (int4 main body + scalar tail)
    for (int e = c0 + tid * 4; e + 4 <= c1; e += 1024) {
        int4 d4 = *(const int4*)(dst + e);
        atomicAdd(&lhist[d4.x >> BSH2], 1);
        atomicAdd(&lhist[d4.y >> BSH2], 1);
        atomicAdd(&lhist[d4.z >> BSH2], 1);
        atomicAdd(&lhist[d4.w >> BSH2], 1);
    }
    int tail = c0 + ((c1 - c0) & ~3);
    for (int e = tail + tid; e < c1; e += 256)
        atomicAdd(&lhist[dst[e] >> BSH2], 1);
    __syncthreads();

    // 2: exclusive scan over 256 counters (Hillis-Steele)
    {
        int v = lhist[tid];
        lbase[tid] = v;
        __syncthreads();
        for (int o = 1; o < 256; o <<= 1) {
            int t = (tid >= o) ? lbase[tid - o] : 0;
            __syncthreads();
            lbase[tid] += t;
            __syncthreads();
        }
        int excl = lbase[tid] - v;
        __syncthreads();
        lbase[tid] = excl;
        lcur[tid] = excl;
    }
    __syncthreads();

    // 3: place chunk into LDS sorted by bucket
    for (int e = c0 + tid * 4; e + 4 <= c1; e += 1024) {
        int4 d4 = *(const int4*)(dst + e);
        int4 s4 = *(const int4*)(src + e);
        int k, pos;
        k = d4.x >> BSH2; pos = atomicAdd(&lcur[k], 1);
        staged[pos] = s4.x | ((d4.x & (NPB - 1)) << 20);
        k = d4.y >> BSH2; pos = atomicAdd(&lcur[k], 1);
        staged[pos] = s4.y | ((d4.y & (NPB - 1)) << 20);
        k = d4.z >> BSH2; pos = atomicAdd(&lcur[k], 1);
        staged[pos] = s4.z | ((d4.z & (NPB - 1)) << 20);
        k = d4.w >> BSH2; pos = atomicAdd(&lcur[k], 1);
        staged[pos] = s4.w | ((d4.w & (NPB - 1)) << 20);
    }
    for (int e = tail + tid; e < c1; e += 256) {
        int d = dst[e];
        int k = d >> BSH2;
        int pos = atomicAdd(&lcur[k], 1);
        staged[pos] = src[e] | ((d & (NPB - 1)) << 20);
    }
    __syncthreads();

    // 4: flush runs; one wave per bucket round-robin
    int wid = tid >> 6, lane = tid & 63;
    for (int k = wid; k < NB2; k += 4) {
        int c = lhist[k];
        if (!c) continue;
        int c16 = (c + 15) & ~15;
        int g;
        if (lane == 0) g = atomicAdd(&gcur[k << 4], c16);
        g = __shfl(g, 0, 64);
        int base = lbase[k];
        for (int i = lane; i < c16; i += 64)
            packed[g + i] = (i < c) ? staged[base + i] : -1;
    }
}

// ---------------- build: per-bucket CSR + norms ----------------
// one block per bucket: sweep region (skip sentinels) -> per-node counts ->
// scan -> row_beg/row_cnt/norm/norm2 -> second sweep places compacted csr.
__global__ __launch_bounds__(256) void bucket_csr(const int* __restrict__ packed,
                                                  const int* __restrict__ gcur,
                                                  int* __restrict__ row_beg,
                                                  int* __restrict__ row_cnt,
                                                  float* __restrict__ norm,
                                                  float* __restrict__ norm2,
                                                  int* __restrict__ csr,
                                                  int N, int NB2) {
    __shared__ int cnt[NPB];
    __shared__ int loc[NPB];
    __shared__ int pre[256];
    int b = blockIdx.x;
    int tid = threadIdx.x;
    cnt[tid] = 0; cnt[tid + 256] = 0;
    __syncthreads();

    int rbeg = b * CAPP;
    int rend = gcur[b << 4];
    // sweep 1: per-node counts
    for (int e = rbeg + tid; e < rend; e += 256) {
        int p = packed[e];
        if (p != -1) atomicAdd(&cnt[(p >> 20) & (NPB - 1)], 1);
    }
    __syncthreads();
    // pairwise scan of 512 counters with 256 threads
    int a0 = cnt[2 * tid], a1 = cnt[2 * tid + 1];
    int s = a0 + a1;
    pre[tid] = s;
    __syncthreads();
    for (int o = 1; o < 256; o <<= 1) {
        int t = (tid >= o) ? pre[tid - o] : 0;
        __syncthreads();
        pre[tid] += t;
        __syncthreads();
    }
    int ep = pre[tid] - s;
    loc[2 * tid] = ep;
    loc[2 * tid + 1] = ep + a0;
    __syncthreads();

    // per-node outputs
    int cbase = b * CAP2;
    for (int j = 0; j < 2; j++) {
        int idx = tid + j * 256;
        int n = (b << BSH2) + idx;
        if (n < N) {
            int c = cnt[idx];
            row_beg[n] = cbase + loc[idx];
            row_cnt[n] = c;
            float df = (float)c; df = df < 1.0f ? 1.0f : df;
            float r = rsqrtf(df);
            norm[n] = r;
            norm2[n] = r * r;
        }
    }
    __syncthreads();
    // sweep 2: place compacted csr (loc doubles as placement cursor)
    for (int e = rbeg + tid; e < rend; e += 256) {
        int p = packed[e];
        if (p != -1) {
            int l = (p >> 20) & (NPB - 1);
            int pos = atomicAdd(&loc[l], 1);
            csr[cbase + pos] = p & 0xFFFFF;
        }
    }
}

// ---------------- gather: one wave per node, unroll-2 ----------------

template <bool HS>
__global__ __launch_bounds__(256) void gather_csr(const float* __restrict__ x,
                                                  const float* __restrict__ scale,
                                                  const int* __restrict__ row_beg,
                                                  const int* __restrict__ row_cnt,
                                                  const int* __restrict__ csr,
                                                  const float* __restrict__ post,
                                                  float* __restrict__ out, int N) {
    int w = blockIdx.x * 4 + (threadIdx.x >> 6);
    if (w >= N) return;
    int lane = threadIdx.x & 63;
    int g = lane >> 4;
    int sub = lane & 15;
    int beg = row_beg[w];
    int end = beg + row_cnt[w];
    const float4* x4 = (const float4*)x;
    float ax = 0.f, ay = 0.f, az = 0.f, aw = 0.f;
    int e = beg + g;
    for (; e + 4 < end; e += 8) {
        int s0 = csr[e];
        int s1 = csr[e + 4];
        float c0 = HS ? scale[s0] : 1.0f;
        float c1 = HS ? scale[s1] : 1.0f;
        float4 v0 = x4[s0 * (D / 4) + sub];
        float4 v1 = x4[s1 * (D / 4) + sub];
        ax += v0.x * c0; ay += v0.y * c0; az += v0.z * c0; aw += v0.w * c0;
        ax += v1.x * c1; ay += v1.y * c1; az += v1.z * c1; aw += v1.w * c1;
    }
    if (e < end) {
        int s0 = csr[e];
        float c0 = HS ? scale[s0] : 1.0f;
        float4 v0 = x4[s0 * (D / 4) + sub];
        ax += v0.x * c0; ay += v0.y * c0; az += v0.z * c0; aw += v0.w * c0;
    }
    ax += __shfl_xor(ax, 16, 64); ay += __shfl_xor(ay, 16, 64);
    az += __shfl_xor(az, 16, 64); aw += __shfl_xor(aw, 16, 64);
    ax += __shfl_xor(ax, 32, 64); ay += __shfl_xor(ay, 32, 64);
    az += __shfl_xor(az, 32, 64); aw += __shfl_xor(aw, 32, 64);
    if (g == 0) {
        float pn = post[w];
        float4 r; r.x = ax * pn; r.y = ay * pn; r.z = az * pn; r.w = aw * pn;
        ((float4*)(out + (long)w * D))[sub] = r;
    }
}

// ---------------- fallback (atomic push, round-1) ----------------

__global__ void deg_kernel_f(const int* __restrict__ dst, float* __restrict__ deg, int E) {
    int e = blockIdx.x * blockDim.x + threadIdx.x;
    if (e < E) unsafeAtomicAdd(&deg[dst[e]], 1.0f);
}

__global__ void norm_kernel_f(float* __restrict__ deg_norm, float* __restrict__ norm2, int N) {
    int i = blockIdx.x * blockDim.x + threadIdx.x;
    if (i < N) {
        float d = deg_norm[i];
        d = d < 1.0f ? 1.0f : d;
        float r = rsqrtf(d);
        deg_norm[i] = r;
        norm2[i] = r * r;
    }
}

__global__ void scatter_kernel(const float* __restrict__ x,
                               const float* __restrict__ scale,
                               const int* __restrict__ src,
                               const int* __restrict__ dst,
                               float* __restrict__ out, int E) {
    long idx = (long)blockIdx.x * blockDim.x + threadIdx.x;
    int e = (int)(idx >> 6);
    int lane = (int)(idx & 63);
    if (e < E) {
        int s = src[e];
        int d0 = dst[e];
        float v = x[(long)s * D + lane] * scale[s];
        unsafeAtomicAdd(&out[(long)d0 * D + lane], v);
    }
}

__global__ void scale_kernel(float* __restrict__ out, const float* __restrict__ norm, long n) {
    long i = (long)blockIdx.x * blockDim.x + threadIdx.x;
    if (i < n) out[i] *= norm[i >> 6];
}

// ---------------- launch ----------------

extern "C" void kernel_launch(void* const* d_in, const int* in_sizes, int n_in,
                              void* d_out, int out_size, void* d_ws, size_t ws_size,
                              hipStream_t stream) {
    const float* feat = (const float*)d_in[0];
    const int*   src  = (const int*)d_in[1];
    const int*   dst  = (const int*)d_in[2];
    float* out = (float*)d_out;

    const int N = in_sizes[0] / D;   // 100000
    const int E = in_sizes[1];       // 1200000
    const long ND = (long)N * D;
    const int NB2 = (N + NPB - 1) >> BSH2;   // 512-node buckets

    // ws layout (4B elems):
    //   gcur[NB2_MAX*16] | row_beg[N] | row_cnt[N] | norm[N] | norm2[N] |
    //   csr[NB2*CAP2] | pad | buf1[max(ND, NB2*CAPP)]
    //   (packed regions alias buf1 -- dead before gather1 writes buf1)
    long o_gcur = 0;
    long o_rbeg = o_gcur + NB2_MAX * 16;
    long o_rcnt = o_rbeg + N;
    long o_norm = o_rcnt + N;
    long o_norm2 = o_norm + N;
    long o_csr  = (o_norm2 + N + 3) & ~3L;
    long o_buf1 = (o_csr + (long)NB2 * CAP2 + 3) & ~3L;
    long pk_len = (long)NB2 * CAPP;
    long buf1_len = (ND > pk_len) ? ND : pk_len;
    size_t need = (size_t)(o_buf1 + buf1_len) * 4;

    if (ws_size >= need && N <= (1 << 20) && NB2 <= NB2_MAX) {
        int*   bi = (int*)d_ws;
        float* bf = (float*)d_ws;
        int* gcur    = bi + o_gcur;
        int* row_beg = bi + o_rbeg;
        int* row_cnt = bi + o_rcnt;
        float* norm  = bf + o_norm;
        float* norm2 = bf + o_norm2;
        int* csr     = bi + o_csr;
        float* buf1  = bf + o_buf1;
        int* packed  = (int*)buf1;

        int pblocks = (E + PCHUNK - 1) / PCHUNK;

        init_cursors<<<(NB2 + 255) / 256, 256, 0, stream>>>(gcur, NB2);
        partition_direct<<<pblocks, 256, 0, stream>>>(src, dst, gcur, packed, E, NB2);
        bucket_csr<<<NB2, 256, 0, stream>>>(packed, gcur, row_beg, row_cnt,
                                            norm, norm2, csr, N, NB2);

        int gblocks = (N + 3) / 4;
        // hop 1: buf1 = norm2 ⊙ S(norm ⊙ feat)
        gather_csr<true><<<gblocks, 256, 0, stream>>>(feat, norm, row_beg, row_cnt,
                                                      csr, norm2, buf1, N);
        // hop 2: out = norm ⊙ S(buf1)
        gather_csr<false><<<gblocks, 256, 0, stream>>>(buf1, nullptr, row_beg, row_cnt,
                                                       csr, norm, out, N);
    } else {
        // fallback: atomic push mode
        float* norm  = (float*)d_ws;
        float* norm2 = norm + N;
        float* buf1  = norm2 + N;

        long nz = 2L * N + ND;
        zero_f32<<<(int)((nz + 255) / 256), 256, 0, stream>>>((float*)d_ws, nz);
        zero_f32<<<(int)((ND + 255) / 256), 256, 0, stream>>>(out, ND);
        deg_kernel_f<<<(E + 255) / 256, 256, 0, stream>>>(dst, norm, E);
        norm_kernel_f<<<(N + 255) / 256, 256, 0, stream>>>(norm, norm2, N);
        long work = (long)E * D;
        int blocks = (int)((work + 255) / 256);
        scatter_kernel<<<blocks, 256, 0, stream>>>(feat, norm, src, dst, buf1, E);
        scatter_kernel<<<blocks, 256, 0, stream>>>(buf1, norm2, src, dst, out, E);
        scale_kernel<<<(int)((ND + 255) / 256), 256, 0, stream>>>(out, norm, ND);
    }
}

// Round 8
// 206.141 us; speedup vs baseline: 1.1982x; 1.1306x over previous
//
#include <hip/hip_runtime.h>

#define D 64
#define BSH2 8                   // 256 nodes per coarse bucket
#define NPB 256                  // nodes per bucket
#define NB2_MAX 512              // max buckets (N <= 131072)
#define PCHUNK 4096              // edges per partition block
#define CAPP 6144                // packed region capacity per bucket (incl. pad, x16)
#define CAP2 4096                // csr region capacity per bucket (real edges)

// ---------------- utility ----------------

__global__ void zero_f32(float* __restrict__ p, long n) {
    long i = (long)blockIdx.x * blockDim.x + threadIdx.x;
    long stride = (long)gridDim.x * blockDim.x;
    for (; i < n; i += stride) p[i] = 0.0f;
}

__global__ void init_cursors(int* __restrict__ gcur, int NB2) {
    int i = blockIdx.x * blockDim.x + threadIdx.x;
    if (i < NB2) gcur[i << 4] = i * CAPP;
}

// ---------------- build: single-pass partition ----------------
// Each block: LDS-histogram its chunk -> in-block scan -> sort chunk into LDS
// by bucket -> PARALLEL per-bucket global reservation (one lane per bucket,
// 16-edge aligned) -> fire-and-forget full-line flush (sentinel -1 pads).
// Every 64B line of packed[] is written by exactly one block.
// packed = src | (dst & 255) << 20   (requires N <= 2^20)
__global__ __launch_bounds__(256) void partition_direct(const int* __restrict__ src,
                                                        const int* __restrict__ dst,
                                                        int* __restrict__ gcur,  // stride 16
                                                        int* __restrict__ packed,
                                                        int E, int NB2) {
    __shared__ int staged[PCHUNK];     // 16 KB sorted chunk
    __shared__ int lhist[NB2_MAX];
    __shared__ int lbase[NB2_MAX];
    __shared__ int lcur[NB2_MAX];
    __shared__ int gbase[NB2_MAX];
    __shared__ int pre[256];
    int tid = threadIdx.x;
    int c0 = blockIdx.x * PCHUNK;
    int c1 = c0 + PCHUNK; if (c1 > E) c1 = E;

    lhist[tid] = 0; lhist[tid + 256] = 0;
    __syncthreads();

    // 1: histogram (int4 main body + scalar tail)
    for (int e = c0 + tid * 4; e + 4 <= c1; e += 1024) {
        int4 d4 = *(const int4*)(dst + e);
        atomicAdd(&lhist[d4.x >> BSH2], 1);
        atomicAdd(&lhist[d4.y >> BSH2], 1);
        atomicAdd(&lhist[d4.z >> BSH2], 1);
        atomicAdd(&lhist[d4.w >> BSH2], 1);
    }
    int tail = c0 + ((c1 - c0) & ~3);
    for (int e = tail + tid; e < c1; e += 256)
        atomicAdd(&lhist[dst[e] >> BSH2], 1);
    __syncthreads();

    // 2: pairwise exclusive scan over 512 counters (each thread owns 2)
    int a0 = lhist[2 * tid], a1 = lhist[2 * tid + 1];
    int s = a0 + a1;
    pre[tid] = s;
    __syncthreads();
    for (int o = 1; o < 256; o <<= 1) {
        int t = (tid >= o) ? pre[tid - o] : 0;
        __syncthreads();
        pre[tid] += t;
        __syncthreads();
    }
    int ep = pre[tid] - s;
    lbase[2 * tid] = ep;       lbase[2 * tid + 1] = ep + a0;
    lcur[2 * tid]  = ep;       lcur[2 * tid + 1]  = ep + a0;
    __syncthreads();

    // 3: place chunk into LDS sorted by bucket
    for (int e = c0 + tid * 4; e + 4 <= c1; e += 1024) {
        int4 d4 = *(const int4*)(dst + e);
        int4 s4 = *(const int4*)(src + e);
        int k, pos;
        k = d4.x >> BSH2; pos = atomicAdd(&lcur[k], 1);
        staged[pos] = s4.x | ((d4.x & (NPB - 1)) << 20);
        k = d4.y >> BSH2; pos = atomicAdd(&lcur[k], 1);
        staged[pos] = s4.y | ((d4.y & (NPB - 1)) << 20);
        k = d4.z >> BSH2; pos = atomicAdd(&lcur[k], 1);
        staged[pos] = s4.z | ((d4.z & (NPB - 1)) << 20);
        k = d4.w >> BSH2; pos = atomicAdd(&lcur[k], 1);
        staged[pos] = s4.w | ((d4.w & (NPB - 1)) << 20);
    }
    for (int e = tail + tid; e < c1; e += 256) {
        int d = dst[e];
        int k = d >> BSH2;
        int pos = atomicAdd(&lcur[k], 1);
        staged[pos] = src[e] | ((d & (NPB - 1)) << 20);
    }
    __syncthreads();

    // 4: parallel reservations — 2 global-atomic round trips total
    for (int i = tid; i < NB2; i += 256) {
        int c = lhist[i];
        gbase[i] = c ? atomicAdd(&gcur[i << 4], (c + 15) & ~15) : 0;
    }
    __syncthreads();

    // 5: flush — 16-lane groups stream full 64B lines, no waits
    int grp = tid >> 4, sub = tid & 15;
    for (int k = grp; k < NB2; k += 16) {
        int c = lhist[k];
        if (!c) continue;
        int c16 = (c + 15) & ~15;
        int g = gbase[k], base = lbase[k];
        for (int i = sub; i < c16; i += 16)
            packed[g + i] = (i < c) ? staged[base + i] : -1;
    }
}

// ---------------- build: per-bucket CSR + norms ----------------
// one block per bucket; regions are 16-padded so int4 sweeps are exact.
__global__ __launch_bounds__(256) void bucket_csr(const int* __restrict__ packed,
                                                  const int* __restrict__ gcur,
                                                  int* __restrict__ row_beg,
                                                  int* __restrict__ row_cnt,
                                                  float* __restrict__ norm,
                                                  float* __restrict__ norm2,
                                                  int* __restrict__ csr,
                                                  int N, int NB2) {
    __shared__ int cnt[NPB];
    __shared__ int loc[NPB];
    int b = blockIdx.x;
    int tid = threadIdx.x;
    cnt[tid] = 0;
    __syncthreads();

    int rbeg = b * CAPP;
    int rend = gcur[b << 4];
    // sweep 1: per-node counts (int4)
    for (int e = rbeg + tid * 4; e + 4 <= rend; e += 1024) {
        int4 p4 = *(const int4*)(packed + e);
        if (p4.x != -1) atomicAdd(&cnt[(p4.x >> 20) & (NPB - 1)], 1);
        if (p4.y != -1) atomicAdd(&cnt[(p4.y >> 20) & (NPB - 1)], 1);
        if (p4.z != -1) atomicAdd(&cnt[(p4.z >> 20) & (NPB - 1)], 1);
        if (p4.w != -1) atomicAdd(&cnt[(p4.w >> 20) & (NPB - 1)], 1);
    }
    __syncthreads();
    // exclusive scan over 256 counters
    int v = cnt[tid];
    loc[tid] = v;
    __syncthreads();
    for (int o = 1; o < 256; o <<= 1) {
        int t = (tid >= o) ? loc[tid - o] : 0;
        __syncthreads();
        loc[tid] += t;
        __syncthreads();
    }
    int ep = loc[tid] - v;

    // per-node outputs
    int cbase = b * CAP2;
    int node = (b << BSH2) + tid;
    if (node < N) {
        row_beg[node] = cbase + ep;
        row_cnt[node] = v;
        float df = (float)v; df = df < 1.0f ? 1.0f : df;
        float r = rsqrtf(df);
        norm[node] = r;
        norm2[node] = r * r;
    }
    __syncthreads();
    loc[tid] = ep;           // repurpose as placement cursor
    __syncthreads();
    // sweep 2: place compacted csr (int4)
    for (int e = rbeg + tid * 4; e + 4 <= rend; e += 1024) {
        int4 p4 = *(const int4*)(packed + e);
        int l, pos;
        if (p4.x != -1) { l = (p4.x >> 20) & (NPB - 1); pos = atomicAdd(&loc[l], 1); csr[cbase + pos] = p4.x & 0xFFFFF; }
        if (p4.y != -1) { l = (p4.y >> 20) & (NPB - 1); pos = atomicAdd(&loc[l], 1); csr[cbase + pos] = p4.y & 0xFFFFF; }
        if (p4.z != -1) { l = (p4.z >> 20) & (NPB - 1); pos = atomicAdd(&loc[l], 1); csr[cbase + pos] = p4.z & 0xFFFFF; }
        if (p4.w != -1) { l = (p4.w >> 20) & (NPB - 1); pos = atomicAdd(&loc[l], 1); csr[cbase + pos] = p4.w & 0xFFFFF; }
    }
}

// ---------------- gather: one wave per node, unroll-2 ----------------

template <bool HS>
__global__ __launch_bounds__(256) void gather_csr(const float* __restrict__ x,
                                                  const float* __restrict__ scale,
                                                  const int* __restrict__ row_beg,
                                                  const int* __restrict__ row_cnt,
                                                  const int* __restrict__ csr,
                                                  const float* __restrict__ post,
                                                  float* __restrict__ out, int N) {
    int w = blockIdx.x * 4 + (threadIdx.x >> 6);
    if (w >= N) return;
    int lane = threadIdx.x & 63;
    int g = lane >> 4;
    int sub = lane & 15;
    int beg = row_beg[w];
    int end = beg + row_cnt[w];
    const float4* x4 = (const float4*)x;
    float ax = 0.f, ay = 0.f, az = 0.f, aw = 0.f;
    int e = beg + g;
    for (; e + 4 < end; e += 8) {
        int s0 = csr[e];
        int s1 = csr[e + 4];
        float c0 = HS ? scale[s0] : 1.0f;
        float c1 = HS ? scale[s1] : 1.0f;
        float4 v0 = x4[s0 * (D / 4) + sub];
        float4 v1 = x4[s1 * (D / 4) + sub];
        ax += v0.x * c0; ay += v0.y * c0; az += v0.z * c0; aw += v0.w * c0;
        ax += v1.x * c1; ay += v1.y * c1; az += v1.z * c1; aw += v1.w * c1;
    }
    if (e < end) {
        int s0 = csr[e];
        float c0 = HS ? scale[s0] : 1.0f;
        float4 v0 = x4[s0 * (D / 4) + sub];
        ax += v0.x * c0; ay += v0.y * c0; az += v0.z * c0; aw += v0.w * c0;
    }
    ax += __shfl_xor(ax, 16, 64); ay += __shfl_xor(ay, 16, 64);
    az += __shfl_xor(az, 16, 64); aw += __shfl_xor(aw, 16, 64);
    ax += __shfl_xor(ax, 32, 64); ay += __shfl_xor(ay, 32, 64);
    az += __shfl_xor(az, 32, 64); aw += __shfl_xor(aw, 32, 64);
    if (g == 0) {
        float pn = post[w];
        float4 r; r.x = ax * pn; r.y = ay * pn; r.z = az * pn; r.w = aw * pn;
        ((float4*)(out + (long)w * D))[sub] = r;
    }
}

// ---------------- fallback (atomic push, round-1) ----------------

__global__ void deg_kernel_f(const int* __restrict__ dst, float* __restrict__ deg, int E) {
    int e = blockIdx.x * blockDim.x + threadIdx.x;
    if (e < E) unsafeAtomicAdd(&deg[dst[e]], 1.0f);
}

__global__ void norm_kernel_f(float* __restrict__ deg_norm, float* __restrict__ norm2, int N) {
    int i = blockIdx.x * blockDim.x + threadIdx.x;
    if (i < N) {
        float d = deg_norm[i];
        d = d < 1.0f ? 1.0f : d;
        float r = rsqrtf(d);
        deg_norm[i] = r;
        norm2[i] = r * r;
    }
}

__global__ void scatter_kernel(const float* __restrict__ x,
                               const float* __restrict__ scale,
                               const int* __restrict__ src,
                               const int* __restrict__ dst,
                               float* __restrict__ out, int E) {
    long idx = (long)blockIdx.x * blockDim.x + threadIdx.x;
    int e = (int)(idx >> 6);
    int lane = (int)(idx & 63);
    if (e < E) {
        int s = src[e];
        int d0 = dst[e];
        float v = x[(long)s * D + lane] * scale[s];
        unsafeAtomicAdd(&out[(long)d0 * D + lane], v);
    }
}

__global__ void scale_kernel(float* __restrict__ out, const float* __restrict__ norm, long n) {
    long i = (long)blockIdx.x * blockDim.x + threadIdx.x;
    if (i < n) out[i] *= norm[i >> 6];
}

// ---------------- launch ----------------

extern "C" void kernel_launch(void* const* d_in, const int* in_sizes, int n_in,
                              void* d_out, int out_size, void* d_ws, size_t ws_size,
                              hipStream_t stream) {
    const float* feat = (const float*)d_in[0];
    const int*   src  = (const int*)d_in[1];
    const int*   dst  = (const int*)d_in[2];
    float* out = (float*)d_out;

    const int N = in_sizes[0] / D;   // 100000
    const int E = in_sizes[1];       // 1200000
    const long ND = (long)N * D;
    const int NB2 = (N + NPB - 1) >> BSH2;   // 256-node buckets

    // ws layout (4B elems):
    //   gcur[NB2_MAX*16] | row_beg[N] | row_cnt[N] | norm[N] | norm2[N] |
    //   csr[NB2*CAP2] | pad | buf1[max(ND, NB2*CAPP)]
    //   (packed regions alias buf1 -- dead before gather1 writes buf1)
    long o_gcur = 0;
    long o_rbeg = o_gcur + NB2_MAX * 16;
    long o_rcnt = o_rbeg + N;
    long o_norm = o_rcnt + N;
    long o_norm2 = o_norm + N;
    long o_csr  = (o_norm2 + N + 3) & ~3L;
    long o_buf1 = (o_csr + (long)NB2 * CAP2 + 3) & ~3L;
    long pk_len = (long)NB2 * CAPP;
    long buf1_len = (ND > pk_len) ? ND : pk_len;
    size_t need = (size_t)(o_buf1 + buf1_len) * 4;

    if (ws_size >= need && N <= (1 << 20) && NB2 <= NB2_MAX) {
        int*   bi = (int*)d_ws;
        float* bf = (float*)d_ws;
        int* gcur    = bi + o_gcur;
        int* row_beg = bi + o_rbeg;
        int* row_cnt = bi + o_rcnt;
        float* norm  = bf + o_norm;
        float* norm2 = bf + o_norm2;
        int* csr     = bi + o_csr;
        float* buf1  = bf + o_buf1;
        int* packed  = (int*)buf1;

        int pblocks = (E + PCHUNK - 1) / PCHUNK;

        init_cursors<<<(NB2 + 255) / 256, 256, 0, stream>>>(gcur, NB2);
        partition_direct<<<pblocks, 256, 0, stream>>>(src, dst, gcur, packed, E, NB2);
        bucket_csr<<<NB2, 256, 0, stream>>>(packed, gcur, row_beg, row_cnt,
                                            norm, norm2, csr, N, NB2);

        int gblocks = (N + 3) / 4;
        // hop 1: buf1 = norm2 ⊙ S(norm ⊙ feat)
        gather_csr<true><<<gblocks, 256, 0, stream>>>(feat, norm, row_beg, row_cnt,
                                                      csr, norm2, buf1, N);
        // hop 2: out = norm ⊙ S(buf1)
        gather_csr<false><<<gblocks, 256, 0, stream>>>(buf1, nullptr, row_beg, row_cnt,
                                                       csr, norm, out, N);
    } else {
        // fallback: atomic push mode
        float* norm  = (float*)d_ws;
        float* norm2 = norm + N;
        float* buf1  = norm2 + N;

        long nz = 2L * N + ND;
        zero_f32<<<(int)((nz + 255) / 256), 256, 0, stream>>>((float*)d_ws, nz);
        zero_f32<<<(int)((ND + 255) / 256), 256, 0, stream>>>(out, ND);
        deg_kernel_f<<<(E + 255) / 256, 256, 0, stream>>>(dst, norm, E);
        norm_kernel_f<<<(N + 255) / 256, 256, 0, stream>>>(norm, norm2, N);
        long work = (long)E * D;
        int blocks = (int)((work + 255) / 256);
        scatter_kernel<<<blocks, 256, 0, stream>>>(feat, norm, src, dst, buf1, E);
        scatter_kernel<<<blocks, 256, 0, stream>>>(buf1, norm2, src, dst, out, E);
        scale_kernel<<<(int)((ND + 255) / 256), 256, 0, stream>>>(out, norm, ND);
    }
}

// Round 9
// 199.016 us; speedup vs baseline: 1.2411x; 1.0358x over previous
//
#include <hip/hip_runtime.h>

#define D 64
#define BSH2 8                   // 256 nodes per coarse bucket
#define NPB 256                  // nodes per bucket
#define NB2_MAX 512              // max buckets (N <= 131072)
#define PCHUNK 4096              // edges per partition block
#define CAPP 6144                // packed region capacity per bucket (incl. pad, x16)
#define CAP2 4096                // csr region capacity per bucket (real edges)

// ---------------- utility ----------------

__global__ void zero_f32(float* __restrict__ p, long n) {
    long i = (long)blockIdx.x * blockDim.x + threadIdx.x;
    long stride = (long)gridDim.x * blockDim.x;
    for (; i < n; i += stride) p[i] = 0.0f;
}

__global__ void init_cursors(int* __restrict__ gcur, int NB2) {
    int i = blockIdx.x * blockDim.x + threadIdx.x;
    if (i < NB2) gcur[i << 4] = i * CAPP;
}

// ---------------- build: single-pass partition (1024 threads) ----------------
// Same structure/grid/padding as r8 but 4x fatter blocks: each of the serial
// phases (hist -> scan -> LDS sort -> flush) is 4x shorter and 16 waves hide
// each other's latencies. packed = src | (dst & 255) << 20  (N <= 2^20)
__global__ __launch_bounds__(1024) void partition_direct(const int* __restrict__ src,
                                                         const int* __restrict__ dst,
                                                         int* __restrict__ gcur,  // stride 16
                                                         int* __restrict__ packed,
                                                         int E, int NB2) {
    __shared__ int staged[PCHUNK];     // 16 KB sorted chunk
    __shared__ int lhist[NB2_MAX];
    __shared__ int lbase[NB2_MAX];
    __shared__ int lcur[NB2_MAX];
    __shared__ int gbase[NB2_MAX];
    __shared__ int pre[NB2_MAX];
    int tid = threadIdx.x;
    int c0 = blockIdx.x * PCHUNK;
    int c1 = c0 + PCHUNK; if (c1 > E) c1 = E;

    if (tid < NB2_MAX) lhist[tid] = 0;
    __syncthreads();

    // 1: histogram — each thread one int4 (PCHUNK = 4*1024)
    for (int e = c0 + tid * 4; e + 4 <= c1; e += 4096) {
        int4 d4 = *(const int4*)(dst + e);
        atomicAdd(&lhist[d4.x >> BSH2], 1);
        atomicAdd(&lhist[d4.y >> BSH2], 1);
        atomicAdd(&lhist[d4.z >> BSH2], 1);
        atomicAdd(&lhist[d4.w >> BSH2], 1);
    }
    int tail = c0 + ((c1 - c0) & ~3);
    for (int e = tail + tid; e < c1; e += 1024)
        atomicAdd(&lhist[dst[e] >> BSH2], 1);
    __syncthreads();

    // 2: exclusive scan over 512 counters (Hillis-Steele, lanes 0..511 own one)
    int v = (tid < NB2_MAX) ? lhist[tid] : 0;
    if (tid < NB2_MAX) pre[tid] = v;
    __syncthreads();
    for (int o = 1; o < NB2_MAX; o <<= 1) {
        int t = (tid < NB2_MAX && tid >= o) ? pre[tid - o] : 0;
        __syncthreads();
        if (tid < NB2_MAX) pre[tid] += t;
        __syncthreads();
    }
    if (tid < NB2_MAX) {
        int excl = pre[tid] - v;
        lbase[tid] = excl;
        lcur[tid] = excl;
    }
    __syncthreads();

    // 3: place chunk into LDS sorted by bucket
    for (int e = c0 + tid * 4; e + 4 <= c1; e += 4096) {
        int4 d4 = *(const int4*)(dst + e);
        int4 s4 = *(const int4*)(src + e);
        int k, pos;
        k = d4.x >> BSH2; pos = atomicAdd(&lcur[k], 1);
        staged[pos] = s4.x | ((d4.x & (NPB - 1)) << 20);
        k = d4.y >> BSH2; pos = atomicAdd(&lcur[k], 1);
        staged[pos] = s4.y | ((d4.y & (NPB - 1)) << 20);
        k = d4.z >> BSH2; pos = atomicAdd(&lcur[k], 1);
        staged[pos] = s4.z | ((d4.z & (NPB - 1)) << 20);
        k = d4.w >> BSH2; pos = atomicAdd(&lcur[k], 1);
        staged[pos] = s4.w | ((d4.w & (NPB - 1)) << 20);
    }
    for (int e = tail + tid; e < c1; e += 1024) {
        int d = dst[e];
        int k = d >> BSH2;
        int pos = atomicAdd(&lcur[k], 1);
        staged[pos] = src[e] | ((d & (NPB - 1)) << 20);
    }
    __syncthreads();

    // 4: parallel reservations — one global-atomic round trip
    if (tid < NB2_MAX && tid < NB2) {
        int c = lhist[tid];
        gbase[tid] = c ? atomicAdd(&gcur[tid << 4], (c + 15) & ~15) : 0;
    }
    __syncthreads();

    // 5: flush — 64 groups of 16 lanes stream full 64B lines, fire-and-forget
    int grp = tid >> 4, sub = tid & 15;
    for (int k = grp; k < NB2; k += 64) {
        int c = lhist[k];
        if (!c) continue;
        int c16 = (c + 15) & ~15;
        int g = gbase[k], base = lbase[k];
        for (int i = sub; i < c16; i += 16)
            packed[g + i] = (i < c) ? staged[base + i] : -1;
    }
}

// ---------------- build: per-bucket CSR + norms (1024 threads) ----------------
__global__ __launch_bounds__(1024) void bucket_csr(const int* __restrict__ packed,
                                                   const int* __restrict__ gcur,
                                                   int* __restrict__ row_beg,
                                                   int* __restrict__ row_cnt,
                                                   float* __restrict__ norm,
                                                   float* __restrict__ norm2,
                                                   int* __restrict__ csr,
                                                   int N, int NB2) {
    __shared__ int cnt[NPB];
    __shared__ int loc[NPB];
    int b = blockIdx.x;
    int tid = threadIdx.x;
    if (tid < NPB) cnt[tid] = 0;
    __syncthreads();

    int rbeg = b * CAPP;
    int rend = gcur[b << 4];
    // sweep 1: per-node counts (int4, regions are 16-aligned + sentinel-padded)
    for (int e = rbeg + tid * 4; e + 4 <= rend; e += 4096) {
        int4 p4 = *(const int4*)(packed + e);
        if (p4.x != -1) atomicAdd(&cnt[(p4.x >> 20) & (NPB - 1)], 1);
        if (p4.y != -1) atomicAdd(&cnt[(p4.y >> 20) & (NPB - 1)], 1);
        if (p4.z != -1) atomicAdd(&cnt[(p4.z >> 20) & (NPB - 1)], 1);
        if (p4.w != -1) atomicAdd(&cnt[(p4.w >> 20) & (NPB - 1)], 1);
    }
    __syncthreads();
    // exclusive scan over 256 counters on lanes 0..255 (all threads sync)
    int v = (tid < NPB) ? cnt[tid] : 0;
    if (tid < NPB) loc[tid] = v;
    __syncthreads();
    for (int o = 1; o < NPB; o <<= 1) {
        int t = (tid < NPB && tid >= o) ? loc[tid - o] : 0;
        __syncthreads();
        if (tid < NPB) loc[tid] += t;
        __syncthreads();
    }
    int ep = (tid < NPB) ? (loc[tid] - v) : 0;

    // per-node outputs
    int cbase = b * CAP2;
    if (tid < NPB) {
        int node = (b << BSH2) + tid;
        if (node < N) {
            row_beg[node] = cbase + ep;
            row_cnt[node] = v;
            float df = (float)v; df = df < 1.0f ? 1.0f : df;
            float r = rsqrtf(df);
            norm[node] = r;
            norm2[node] = r * r;
        }
    }
    __syncthreads();
    if (tid < NPB) loc[tid] = ep;   // repurpose as placement cursor
    __syncthreads();
    // sweep 2: place compacted csr (int4)
    for (int e = rbeg + tid * 4; e + 4 <= rend; e += 4096) {
        int4 p4 = *(const int4*)(packed + e);
        int l, pos;
        if (p4.x != -1) { l = (p4.x >> 20) & (NPB - 1); pos = atomicAdd(&loc[l], 1); csr[cbase + pos] = p4.x & 0xFFFFF; }
        if (p4.y != -1) { l = (p4.y >> 20) & (NPB - 1); pos = atomicAdd(&loc[l], 1); csr[cbase + pos] = p4.y & 0xFFFFF; }
        if (p4.z != -1) { l = (p4.z >> 20) & (NPB - 1); pos = atomicAdd(&loc[l], 1); csr[cbase + pos] = p4.z & 0xFFFFF; }
        if (p4.w != -1) { l = (p4.w >> 20) & (NPB - 1); pos = atomicAdd(&loc[l], 1); csr[cbase + pos] = p4.w & 0xFFFFF; }
    }
}

// ---------------- gather: one wave per node, unroll-2 (unchanged) ----------------

template <bool HS>
__global__ __launch_bounds__(256) void gather_csr(const float* __restrict__ x,
                                                  const float* __restrict__ scale,
                                                  const int* __restrict__ row_beg,
                                                  const int* __restrict__ row_cnt,
                                                  const int* __restrict__ csr,
                                                  const float* __restrict__ post,
                                                  float* __restrict__ out, int N) {
    int w = blockIdx.x * 4 + (threadIdx.x >> 6);
    if (w >= N) return;
    int lane = threadIdx.x & 63;
    int g = lane >> 4;
    int sub = lane & 15;
    int beg = row_beg[w];
    int end = beg + row_cnt[w];
    const float4* x4 = (const float4*)x;
    float ax = 0.f, ay = 0.f, az = 0.f, aw = 0.f;
    int e = beg + g;
    for (; e + 4 < end; e += 8) {
        int s0 = csr[e];
        int s1 = csr[e + 4];
        float c0 = HS ? scale[s0] : 1.0f;
        float c1 = HS ? scale[s1] : 1.0f;
        float4 v0 = x4[s0 * (D / 4) + sub];
        float4 v1 = x4[s1 * (D / 4) + sub];
        ax += v0.x * c0; ay += v0.y * c0; az += v0.z * c0; aw += v0.w * c0;
        ax += v1.x * c1; ay += v1.y * c1; az += v1.z * c1; aw += v1.w * c1;
    }
    if (e < end) {
        int s0 = csr[e];
        float c0 = HS ? scale[s0] : 1.0f;
        float4 v0 = x4[s0 * (D / 4) + sub];
        ax += v0.x * c0; ay += v0.y * c0; az += v0.z * c0; aw += v0.w * c0;
    }
    ax += __shfl_xor(ax, 16, 64); ay += __shfl_xor(ay, 16, 64);
    az += __shfl_xor(az, 16, 64); aw += __shfl_xor(aw, 16, 64);
    ax += __shfl_xor(ax, 32, 64); ay += __shfl_xor(ay, 32, 64);
    az += __shfl_xor(az, 32, 64); aw += __shfl_xor(aw, 32, 64);
    if (g == 0) {
        float pn = post[w];
        float4 r; r.x = ax * pn; r.y = ay * pn; r.z = az * pn; r.w = aw * pn;
        ((float4*)(out + (long)w * D))[sub] = r;
    }
}

// ---------------- fallback (atomic push, round-1) ----------------

__global__ void deg_kernel_f(const int* __restrict__ dst, float* __restrict__ deg, int E) {
    int e = blockIdx.x * blockDim.x + threadIdx.x;
    if (e < E) unsafeAtomicAdd(&deg[dst[e]], 1.0f);
}

__global__ void norm_kernel_f(float* __restrict__ deg_norm, float* __restrict__ norm2, int N) {
    int i = blockIdx.x * blockDim.x + threadIdx.x;
    if (i < N) {
        float d = deg_norm[i];
        d = d < 1.0f ? 1.0f : d;
        float r = rsqrtf(d);
        deg_norm[i] = r;
        norm2[i] = r * r;
    }
}

__global__ void scatter_kernel(const float* __restrict__ x,
                               const float* __restrict__ scale,
                               const int* __restrict__ src,
                               const int* __restrict__ dst,
                               float* __restrict__ out, int E) {
    long idx = (long)blockIdx.x * blockDim.x + threadIdx.x;
    int e = (int)(idx >> 6);
    int lane = (int)(idx & 63);
    if (e < E) {
        int s = src[e];
        int d0 = dst[e];
        float v = x[(long)s * D + lane] * scale[s];
        unsafeAtomicAdd(&out[(long)d0 * D + lane], v);
    }
}

__global__ void scale_kernel(float* __restrict__ out, const float* __restrict__ norm, long n) {
    long i = (long)blockIdx.x * blockDim.x + threadIdx.x;
    if (i < n) out[i] *= norm[i >> 6];
}

// ---------------- launch ----------------

extern "C" void kernel_launch(void* const* d_in, const int* in_sizes, int n_in,
                              void* d_out, int out_size, void* d_ws, size_t ws_size,
                              hipStream_t stream) {
    const float* feat = (const float*)d_in[0];
    const int*   src  = (const int*)d_in[1];
    const int*   dst  = (const int*)d_in[2];
    float* out = (float*)d_out;

    const int N = in_sizes[0] / D;   // 100000
    const int E = in_sizes[1];       // 1200000
    const long ND = (long)N * D;
    const int NB2 = (N + NPB - 1) >> BSH2;   // 256-node buckets

    // ws layout (4B elems):
    //   gcur[NB2_MAX*16] | row_beg[N] | row_cnt[N] | norm[N] | norm2[N] |
    //   csr[NB2*CAP2] | pad | buf1[max(ND, NB2*CAPP)]
    //   (packed regions alias buf1 -- dead before gather1 writes buf1)
    long o_gcur = 0;
    long o_rbeg = o_gcur + NB2_MAX * 16;
    long o_rcnt = o_rbeg + N;
    long o_norm = o_rcnt + N;
    long o_norm2 = o_norm + N;
    long o_csr  = (o_norm2 + N + 3) & ~3L;
    long o_buf1 = (o_csr + (long)NB2 * CAP2 + 3) & ~3L;
    long pk_len = (long)NB2 * CAPP;
    long buf1_len = (ND > pk_len) ? ND : pk_len;
    size_t need = (size_t)(o_buf1 + buf1_len) * 4;

    if (ws_size >= need && N <= (1 << 20) && NB2 <= NB2_MAX) {
        int*   bi = (int*)d_ws;
        float* bf = (float*)d_ws;
        int* gcur    = bi + o_gcur;
        int* row_beg = bi + o_rbeg;
        int* row_cnt = bi + o_rcnt;
        float* norm  = bf + o_norm;
        float* norm2 = bf + o_norm2;
        int* csr     = bi + o_csr;
        float* buf1  = bf + o_buf1;
        int* packed  = (int*)buf1;

        int pblocks = (E + PCHUNK - 1) / PCHUNK;

        init_cursors<<<(NB2 + 255) / 256, 256, 0, stream>>>(gcur, NB2);
        partition_direct<<<pblocks, 1024, 0, stream>>>(src, dst, gcur, packed, E, NB2);
        bucket_csr<<<NB2, 1024, 0, stream>>>(packed, gcur, row_beg, row_cnt,
                                             norm, norm2, csr, N, NB2);

        int gblocks = (N + 3) / 4;
        // hop 1: buf1 = norm2 ⊙ S(norm ⊙ feat)
        gather_csr<true><<<gblocks, 256, 0, stream>>>(feat, norm, row_beg, row_cnt,
                                                      csr, norm2, buf1, N);
        // hop 2: out = norm ⊙ S(buf1)
        gather_csr<false><<<gblocks, 256, 0, stream>>>(buf1, nullptr, row_beg, row_cnt,
                                                       csr, norm, out, N);
    } else {
        // fallback: atomic push mode
        float* norm  = (float*)d_ws;
        float* norm2 = norm + N;
        float* buf1  = norm2 + N;

        long nz = 2L * N + ND;
        zero_f32<<<(int)((nz + 255) / 256), 256, 0, stream>>>((float*)d_ws, nz);
        zero_f32<<<(int)((ND + 255) / 256), 256, 0, stream>>>(out, ND);
        deg_kernel_f<<<(E + 255) / 256, 256, 0, stream>>>(dst, norm, E);
        norm_kernel_f<<<(N + 255) / 256, 256, 0, stream>>>(norm, norm2, N);
        long work = (long)E * D;
        int blocks = (int)((work + 255) / 256);
        scatter_kernel<<<blocks, 256, 0, stream>>>(feat, norm, src, dst, buf1, E);
        scatter_kernel<<<blocks, 256, 0, stream>>>(buf1, norm2, src, dst, out, E);
        scale_kernel<<<(int)((ND + 255) / 256), 256, 0, stream>>>(out, norm, ND);
    }
}

// Round 10
// 191.962 us; speedup vs baseline: 1.2867x; 1.0367x over previous
//
#include <hip/hip_runtime.h>
#include <hip/hip_fp16.h>

#define D 64
#define BSH2 8                   // 256 nodes per coarse bucket
#define NPB 256                  // nodes per bucket
#define NB2_MAX 512              // max buckets (N <= 131072)
#define PCHUNK 4096              // edges per partition block
#define CAPP 6144                // packed region capacity per bucket (incl. pad, x16)
#define CAP2 4096                // csr region capacity per bucket (real edges)

// ---------------- utility ----------------

__global__ void zero_f32(float* __restrict__ p, long n) {
    long i = (long)blockIdx.x * blockDim.x + threadIdx.x;
    long stride = (long)gridDim.x * blockDim.x;
    for (; i < n; i += stride) p[i] = 0.0f;
}

__global__ void init_cursors(int* __restrict__ gcur, int NB2) {
    int i = blockIdx.x * blockDim.x + threadIdx.x;
    if (i < NB2) gcur[i << 4] = i * CAPP;
}

// feat16[node*D+j] = half(norm[node] * feat[node*D+j]); one thread per float4
__global__ __launch_bounds__(256) void feat_to_half(const float4* __restrict__ in,
                                                    const float* __restrict__ norm,
                                                    uint2* __restrict__ out, long n4) {
    long i = (long)blockIdx.x * blockDim.x + threadIdx.x;
    if (i < n4) {
        float4 v = in[i];
        float r = norm[i >> 4];
        __half2 a = __floats2half2_rn(v.x * r, v.y * r);
        __half2 b = __floats2half2_rn(v.z * r, v.w * r);
        uint2 u;
        u.x = *(unsigned int*)&a;
        u.y = *(unsigned int*)&b;
        out[i] = u;
    }
}

// ---------------- build: single-pass partition (1024 threads, r9) ----------------
__global__ __launch_bounds__(1024) void partition_direct(const int* __restrict__ src,
                                                         const int* __restrict__ dst,
                                                         int* __restrict__ gcur,  // stride 16
                                                         int* __restrict__ packed,
                                                         int E, int NB2) {
    __shared__ int staged[PCHUNK];     // 16 KB sorted chunk
    __shared__ int lhist[NB2_MAX];
    __shared__ int lbase[NB2_MAX];
    __shared__ int lcur[NB2_MAX];
    __shared__ int gbase[NB2_MAX];
    __shared__ int pre[NB2_MAX];
    int tid = threadIdx.x;
    int c0 = blockIdx.x * PCHUNK;
    int c1 = c0 + PCHUNK; if (c1 > E) c1 = E;

    if (tid < NB2_MAX) lhist[tid] = 0;
    __syncthreads();

    for (int e = c0 + tid * 4; e + 4 <= c1; e += 4096) {
        int4 d4 = *(const int4*)(dst + e);
        atomicAdd(&lhist[d4.x >> BSH2], 1);
        atomicAdd(&lhist[d4.y >> BSH2], 1);
        atomicAdd(&lhist[d4.z >> BSH2], 1);
        atomicAdd(&lhist[d4.w >> BSH2], 1);
    }
    int tail = c0 + ((c1 - c0) & ~3);
    for (int e = tail + tid; e < c1; e += 1024)
        atomicAdd(&lhist[dst[e] >> BSH2], 1);
    __syncthreads();

    int v = (tid < NB2_MAX) ? lhist[tid] : 0;
    if (tid < NB2_MAX) pre[tid] = v;
    __syncthreads();
    for (int o = 1; o < NB2_MAX; o <<= 1) {
        int t = (tid < NB2_MAX && tid >= o) ? pre[tid - o] : 0;
        __syncthreads();
        if (tid < NB2_MAX) pre[tid] += t;
        __syncthreads();
    }
    if (tid < NB2_MAX) {
        int excl = pre[tid] - v;
        lbase[tid] = excl;
        lcur[tid] = excl;
    }
    __syncthreads();

    for (int e = c0 + tid * 4; e + 4 <= c1; e += 4096) {
        int4 d4 = *(const int4*)(dst + e);
        int4 s4 = *(const int4*)(src + e);
        int k, pos;
        k = d4.x >> BSH2; pos = atomicAdd(&lcur[k], 1);
        staged[pos] = s4.x | ((d4.x & (NPB - 1)) << 20);
        k = d4.y >> BSH2; pos = atomicAdd(&lcur[k], 1);
        staged[pos] = s4.y | ((d4.y & (NPB - 1)) << 20);
        k = d4.z >> BSH2; pos = atomicAdd(&lcur[k], 1);
        staged[pos] = s4.z | ((d4.z & (NPB - 1)) << 20);
        k = d4.w >> BSH2; pos = atomicAdd(&lcur[k], 1);
        staged[pos] = s4.w | ((d4.w & (NPB - 1)) << 20);
    }
    for (int e = tail + tid; e < c1; e += 1024) {
        int d = dst[e];
        int k = d >> BSH2;
        int pos = atomicAdd(&lcur[k], 1);
        staged[pos] = src[e] | ((d & (NPB - 1)) << 20);
    }
    __syncthreads();

    if (tid < NB2_MAX && tid < NB2) {
        int c = lhist[tid];
        gbase[tid] = c ? atomicAdd(&gcur[tid << 4], (c + 15) & ~15) : 0;
    }
    __syncthreads();

    int grp = tid >> 4, sub = tid & 15;
    for (int k = grp; k < NB2; k += 64) {
        int c = lhist[k];
        if (!c) continue;
        int c16 = (c + 15) & ~15;
        int g = gbase[k], base = lbase[k];
        for (int i = sub; i < c16; i += 16)
            packed[g + i] = (i < c) ? staged[base + i] : -1;
    }
}

// ---------------- build: per-bucket CSR + norms (1024 threads, r9) ----------------
__global__ __launch_bounds__(1024) void bucket_csr(const int* __restrict__ packed,
                                                   const int* __restrict__ gcur,
                                                   int* __restrict__ row_beg,
                                                   int* __restrict__ row_cnt,
                                                   float* __restrict__ norm,
                                                   float* __restrict__ norm2,
                                                   int* __restrict__ csr,
                                                   int N, int NB2) {
    __shared__ int cnt[NPB];
    __shared__ int loc[NPB];
    int b = blockIdx.x;
    int tid = threadIdx.x;
    if (tid < NPB) cnt[tid] = 0;
    __syncthreads();

    int rbeg = b * CAPP;
    int rend = gcur[b << 4];
    for (int e = rbeg + tid * 4; e + 4 <= rend; e += 4096) {
        int4 p4 = *(const int4*)(packed + e);
        if (p4.x != -1) atomicAdd(&cnt[(p4.x >> 20) & (NPB - 1)], 1);
        if (p4.y != -1) atomicAdd(&cnt[(p4.y >> 20) & (NPB - 1)], 1);
        if (p4.z != -1) atomicAdd(&cnt[(p4.z >> 20) & (NPB - 1)], 1);
        if (p4.w != -1) atomicAdd(&cnt[(p4.w >> 20) & (NPB - 1)], 1);
    }
    __syncthreads();
    int v = (tid < NPB) ? cnt[tid] : 0;
    if (tid < NPB) loc[tid] = v;
    __syncthreads();
    for (int o = 1; o < NPB; o <<= 1) {
        int t = (tid < NPB && tid >= o) ? loc[tid - o] : 0;
        __syncthreads();
        if (tid < NPB) loc[tid] += t;
        __syncthreads();
    }
    int ep = (tid < NPB) ? (loc[tid] - v) : 0;

    int cbase = b * CAP2;
    if (tid < NPB) {
        int node = (b << BSH2) + tid;
        if (node < N) {
            row_beg[node] = cbase + ep;
            row_cnt[node] = v;
            float df = (float)v; df = df < 1.0f ? 1.0f : df;
            float r = rsqrtf(df);
            norm[node] = r;
            norm2[node] = r * r;
        }
    }
    __syncthreads();
    if (tid < NPB) loc[tid] = ep;
    __syncthreads();
    for (int e = rbeg + tid * 4; e + 4 <= rend; e += 4096) {
        int4 p4 = *(const int4*)(packed + e);
        int l, pos;
        if (p4.x != -1) { l = (p4.x >> 20) & (NPB - 1); pos = atomicAdd(&loc[l], 1); csr[cbase + pos] = p4.x & 0xFFFFF; }
        if (p4.y != -1) { l = (p4.y >> 20) & (NPB - 1); pos = atomicAdd(&loc[l], 1); csr[cbase + pos] = p4.y & 0xFFFFF; }
        if (p4.z != -1) { l = (p4.z >> 20) & (NPB - 1); pos = atomicAdd(&loc[l], 1); csr[cbase + pos] = p4.z & 0xFFFFF; }
        if (p4.w != -1) { l = (p4.w >> 20) & (NPB - 1); pos = atomicAdd(&loc[l], 1); csr[cbase + pos] = p4.w & 0xFFFFF; }
    }
}

// ---------------- gather: fp16 rows (128B), one wave per node, unroll-2 ----------------
// x rows are pre-scaled (norm folded at conversion / hop-1 epilogue), so no
// per-edge scale load. OUTHALF: write half rows (hop 1); else fp32 (hop 2).
template <bool OUTHALF>
__global__ __launch_bounds__(256) void gather_h(const __half* __restrict__ x,
                                                const int* __restrict__ row_beg,
                                                const int* __restrict__ row_cnt,
                                                const int* __restrict__ csr,
                                                const float* __restrict__ post,
                                                void* __restrict__ outv, int N) {
    int w = blockIdx.x * 4 + (threadIdx.x >> 6);
    if (w >= N) return;
    int lane = threadIdx.x & 63;
    int g = lane >> 4;
    int sub = lane & 15;
    int beg = row_beg[w];
    int end = beg + row_cnt[w];
    const uint2* x8 = (const uint2*)x;   // 4 halves per uint2; row = 16 uint2
    float ax = 0.f, ay = 0.f, az = 0.f, aw = 0.f;
    int e = beg + g;
    for (; e + 4 < end; e += 8) {
        int s0 = csr[e];
        int s1 = csr[e + 4];
        uint2 u0 = x8[s0 * 16 + sub];
        uint2 u1 = x8[s1 * 16 + sub];
        float2 f;
        f = __half22float2(*(const __half2*)&u0.x); ax += f.x; ay += f.y;
        f = __half22float2(*(const __half2*)&u0.y); az += f.x; aw += f.y;
        f = __half22float2(*(const __half2*)&u1.x); ax += f.x; ay += f.y;
        f = __half22float2(*(const __half2*)&u1.y); az += f.x; aw += f.y;
    }
    if (e < end) {
        int s0 = csr[e];
        uint2 u0 = x8[s0 * 16 + sub];
        float2 f;
        f = __half22float2(*(const __half2*)&u0.x); ax += f.x; ay += f.y;
        f = __half22float2(*(const __half2*)&u0.y); az += f.x; aw += f.y;
    }
    ax += __shfl_xor(ax, 16, 64); ay += __shfl_xor(ay, 16, 64);
    az += __shfl_xor(az, 16, 64); aw += __shfl_xor(aw, 16, 64);
    ax += __shfl_xor(ax, 32, 64); ay += __shfl_xor(ay, 32, 64);
    az += __shfl_xor(az, 32, 64); aw += __shfl_xor(aw, 32, 64);
    if (g == 0) {
        float pn = post[w];
        ax *= pn; ay *= pn; az *= pn; aw *= pn;
        if (OUTHALF) {
            __half2 a = __floats2half2_rn(ax, ay);
            __half2 b = __floats2half2_rn(az, aw);
            uint2 u;
            u.x = *(unsigned int*)&a;
            u.y = *(unsigned int*)&b;
            ((uint2*)outv)[(long)w * 16 + sub] = u;
        } else {
            float4 r; r.x = ax; r.y = ay; r.z = az; r.w = aw;
            ((float4*)outv)[(long)w * 16 + sub] = r;
        }
    }
}

// ---------------- fallback (atomic push, round-1, pure fp32) ----------------

__global__ void deg_kernel_f(const int* __restrict__ dst, float* __restrict__ deg, int E) {
    int e = blockIdx.x * blockDim.x + threadIdx.x;
    if (e < E) unsafeAtomicAdd(&deg[dst[e]], 1.0f);
}

__global__ void norm_kernel_f(float* __restrict__ deg_norm, float* __restrict__ norm2, int N) {
    int i = blockIdx.x * blockDim.x + threadIdx.x;
    if (i < N) {
        float d = deg_norm[i];
        d = d < 1.0f ? 1.0f : d;
        float r = rsqrtf(d);
        deg_norm[i] = r;
        norm2[i] = r * r;
    }
}

__global__ void scatter_kernel(const float* __restrict__ x,
                               const float* __restrict__ scale,
                               const int* __restrict__ src,
                               const int* __restrict__ dst,
                               float* __restrict__ out, int E) {
    long idx = (long)blockIdx.x * blockDim.x + threadIdx.x;
    int e = (int)(idx >> 6);
    int lane = (int)(idx & 63);
    if (e < E) {
        int s = src[e];
        int d0 = dst[e];
        float v = x[(long)s * D + lane] * scale[s];
        unsafeAtomicAdd(&out[(long)d0 * D + lane], v);
    }
}

__global__ void scale_kernel(float* __restrict__ out, const float* __restrict__ norm, long n) {
    long i = (long)blockIdx.x * blockDim.x + threadIdx.x;
    if (i < n) out[i] *= norm[i >> 6];
}

// ---------------- launch ----------------

extern "C" void kernel_launch(void* const* d_in, const int* in_sizes, int n_in,
                              void* d_out, int out_size, void* d_ws, size_t ws_size,
                              hipStream_t stream) {
    const float* feat = (const float*)d_in[0];
    const int*   src  = (const int*)d_in[1];
    const int*   dst  = (const int*)d_in[2];
    float* out = (float*)d_out;

    const int N = in_sizes[0] / D;   // 100000
    const int E = in_sizes[1];       // 1200000
    const long ND = (long)N * D;
    const int NB2 = (N + NPB - 1) >> BSH2;   // 256-node buckets

    // ws layout (4B elems):
    //   gcur[NB2_MAX*16] | row_beg[N] | row_cnt[N] | norm[N] | norm2[N] |
    //   csr[NB2*CAP2] | feat16[ND/2] | buf1h[max(ND/2, NB2*CAPP)]
    //   (packed regions alias buf1h -- dead before gather1 writes buf1h)
    long o_gcur = 0;
    long o_rbeg = o_gcur + NB2_MAX * 16;
    long o_rcnt = o_rbeg + N;
    long o_norm = o_rcnt + N;
    long o_norm2 = o_norm + N;
    long o_csr  = (o_norm2 + N + 3) & ~3L;
    long o_f16  = (o_csr + (long)NB2 * CAP2 + 3) & ~3L;
    long o_buf1 = (o_f16 + ND / 2 + 3) & ~3L;
    long pk_len = (long)NB2 * CAPP;
    long buf1_len = (ND / 2 > pk_len) ? ND / 2 : pk_len;
    size_t need = (size_t)(o_buf1 + buf1_len) * 4;

    if (ws_size >= need && N <= (1 << 20) && NB2 <= NB2_MAX) {
        int*   bi = (int*)d_ws;
        float* bf = (float*)d_ws;
        int* gcur    = bi + o_gcur;
        int* row_beg = bi + o_rbeg;
        int* row_cnt = bi + o_rcnt;
        float* norm  = bf + o_norm;
        float* norm2 = bf + o_norm2;
        int* csr     = bi + o_csr;
        __half* feat16 = (__half*)(bi + o_f16);
        __half* buf1h  = (__half*)(bi + o_buf1);
        int* packed  = bi + o_buf1;

        int pblocks = (E + PCHUNK - 1) / PCHUNK;

        init_cursors<<<(NB2 + 255) / 256, 256, 0, stream>>>(gcur, NB2);
        partition_direct<<<pblocks, 1024, 0, stream>>>(src, dst, gcur, packed, E, NB2);
        bucket_csr<<<NB2, 1024, 0, stream>>>(packed, gcur, row_beg, row_cnt,
                                             norm, norm2, csr, N, NB2);
        // feat16 = norm ⊙ feat (fp16)
        long n4 = ND / 4;
        feat_to_half<<<(int)((n4 + 255) / 256), 256, 0, stream>>>(
            (const float4*)feat, norm, (uint2*)feat16, n4);

        int gblocks = (N + 3) / 4;
        // hop 1: buf1h = half( norm2 ⊙ S(feat16) )
        gather_h<true><<<gblocks, 256, 0, stream>>>(feat16, row_beg, row_cnt,
                                                    csr, norm2, buf1h, N);
        // hop 2: out = norm ⊙ S(buf1h)   (fp32)
        gather_h<false><<<gblocks, 256, 0, stream>>>(buf1h, row_beg, row_cnt,
                                                     csr, norm, out, N);
    } else {
        // fallback: atomic push mode (fp32, needs only 2N+ND floats)
        float* norm  = (float*)d_ws;
        float* norm2 = norm + N;
        float* buf1  = norm2 + N;

        long nz = 2L * N + ND;
        zero_f32<<<(int)((nz + 255) / 256), 256, 0, stream>>>((float*)d_ws, nz);
        zero_f32<<<(int)((ND + 255) / 256), 256, 0, stream>>>(out, ND);
        deg_kernel_f<<<(E + 255) / 256, 256, 0, stream>>>(dst, norm, E);
        norm_kernel_f<<<(N + 255) / 256, 256, 0, stream>>>(norm, norm2, N);
        long work = (long)E * D;
        int blocks = (int)((work + 255) / 256);
        scatter_kernel<<<blocks, 256, 0, stream>>>(feat, norm, src, dst, buf1, E);
        scatter_kernel<<<blocks, 256, 0, stream>>>(buf1, norm2, src, dst, out, E);
        scale_kernel<<<(int)((ND + 255) / 256), 256, 0, stream>>>(out, norm, ND);
    }
}

// Round 11
// 183.283 us; speedup vs baseline: 1.3476x; 1.0473x over previous
//
#include <hip/hip_runtime.h>
#include <hip/hip_fp16.h>

#define D 64
#define BSH2 8                   // 256 nodes per coarse bucket
#define NPB 256                  // nodes per bucket
#define NB2_MAX 512              // max buckets (N <= 131072)
#define PCHUNK 4096              // edges per partition block
#define CAPP 6144                // packed region capacity per bucket (incl. pad, x16)
#define CAP2 4096                // csr region capacity per bucket (real edges)

// ---------------- utility ----------------

__global__ void zero_f32(float* __restrict__ p, long n) {
    long i = (long)blockIdx.x * blockDim.x + threadIdx.x;
    long stride = (long)gridDim.x * blockDim.x;
    for (; i < n; i += stride) p[i] = 0.0f;
}

__global__ void init_cursors(int* __restrict__ gcur, int NB2) {
    int i = blockIdx.x * blockDim.x + threadIdx.x;
    if (i < NB2) gcur[i << 4] = i * CAPP;
}

// feat16[node*D+j] = half(norm[node] * feat[node*D+j]); one thread per float4
__global__ __launch_bounds__(256) void feat_to_half(const float4* __restrict__ in,
                                                    const float* __restrict__ norm,
                                                    uint2* __restrict__ out, long n4) {
    long i = (long)blockIdx.x * blockDim.x + threadIdx.x;
    if (i < n4) {
        float4 v = in[i];
        float r = norm[i >> 4];
        __half2 a = __floats2half2_rn(v.x * r, v.y * r);
        __half2 b = __floats2half2_rn(v.z * r, v.w * r);
        uint2 u;
        u.x = *(unsigned int*)&a;
        u.y = *(unsigned int*)&b;
        out[i] = u;
    }
}

// ---------------- build: single-pass partition (1024 threads) ----------------
__global__ __launch_bounds__(1024) void partition_direct(const int* __restrict__ src,
                                                         const int* __restrict__ dst,
                                                         int* __restrict__ gcur,  // stride 16
                                                         int* __restrict__ packed,
                                                         int E, int NB2) {
    __shared__ int staged[PCHUNK];     // 16 KB sorted chunk
    __shared__ int lhist[NB2_MAX];
    __shared__ int lbase[NB2_MAX];
    __shared__ int lcur[NB2_MAX];
    __shared__ int gbase[NB2_MAX];
    int tid = threadIdx.x;
    int c0 = blockIdx.x * PCHUNK;
    int c1 = c0 + PCHUNK; if (c1 > E) c1 = E;

    if (tid < NB2_MAX) lhist[tid] = 0;
    __syncthreads();

    // 1: histogram
    for (int e = c0 + tid * 4; e + 4 <= c1; e += 4096) {
        int4 d4 = *(const int4*)(dst + e);
        atomicAdd(&lhist[d4.x >> BSH2], 1);
        atomicAdd(&lhist[d4.y >> BSH2], 1);
        atomicAdd(&lhist[d4.z >> BSH2], 1);
        atomicAdd(&lhist[d4.w >> BSH2], 1);
    }
    int tail = c0 + ((c1 - c0) & ~3);
    for (int e = tail + tid; e < c1; e += 1024)
        atomicAdd(&lhist[dst[e] >> BSH2], 1);
    __syncthreads();

    // 2: single-wave exclusive scan over 512 counters (2 barriers total)
    if (tid < 64) {
        const int CPL = NB2_MAX / 64;     // 8 counters per lane
        int tmp[CPL];
        int s = 0;
        int base = tid * CPL;
        #pragma unroll
        for (int j = 0; j < CPL; j++) { tmp[j] = s; s += lhist[base + j]; }
        int incl = s;
        #pragma unroll
        for (int o = 1; o < 64; o <<= 1) {
            int t = __shfl_up(incl, o, 64);
            if (tid >= o) incl += t;
        }
        int excl = incl - s;
        #pragma unroll
        for (int j = 0; j < CPL; j++) {
            lbase[base + j] = excl + tmp[j];
            lcur[base + j]  = excl + tmp[j];
        }
    }
    __syncthreads();

    // 3: place chunk into LDS sorted by bucket
    for (int e = c0 + tid * 4; e + 4 <= c1; e += 4096) {
        int4 d4 = *(const int4*)(dst + e);
        int4 s4 = *(const int4*)(src + e);
        int k, pos;
        k = d4.x >> BSH2; pos = atomicAdd(&lcur[k], 1);
        staged[pos] = s4.x | ((d4.x & (NPB - 1)) << 20);
        k = d4.y >> BSH2; pos = atomicAdd(&lcur[k], 1);
        staged[pos] = s4.y | ((d4.y & (NPB - 1)) << 20);
        k = d4.z >> BSH2; pos = atomicAdd(&lcur[k], 1);
        staged[pos] = s4.z | ((d4.z & (NPB - 1)) << 20);
        k = d4.w >> BSH2; pos = atomicAdd(&lcur[k], 1);
        staged[pos] = s4.w | ((d4.w & (NPB - 1)) << 20);
    }
    for (int e = tail + tid; e < c1; e += 1024) {
        int d = dst[e];
        int k = d >> BSH2;
        int pos = atomicAdd(&lcur[k], 1);
        staged[pos] = src[e] | ((d & (NPB - 1)) << 20);
    }
    __syncthreads();

    // 4: parallel reservations
    if (tid < NB2_MAX && tid < NB2) {
        int c = lhist[tid];
        gbase[tid] = c ? atomicAdd(&gcur[tid << 4], (c + 15) & ~15) : 0;
    }
    __syncthreads();

    // 5: flush — 64 groups of 16 lanes stream full 64B lines
    int grp = tid >> 4, sub = tid & 15;
    for (int k = grp; k < NB2; k += 64) {
        int c = lhist[k];
        if (!c) continue;
        int c16 = (c + 15) & ~15;
        int g = gbase[k], base = lbase[k];
        for (int i = sub; i < c16; i += 16)
            packed[g + i] = (i < c) ? staged[base + i] : -1;
    }
}

// ---------------- build: per-bucket CSR + norms (1024 threads) ----------------
__global__ __launch_bounds__(1024) void bucket_csr(const int* __restrict__ packed,
                                                   const int* __restrict__ gcur,
                                                   int2* __restrict__ rbc,
                                                   float* __restrict__ norm,
                                                   float* __restrict__ norm2,
                                                   int* __restrict__ csr,
                                                   int N, int NB2) {
    __shared__ int cnt[NPB];
    __shared__ int loc[NPB];
    int b = blockIdx.x;
    int tid = threadIdx.x;
    if (tid < NPB) cnt[tid] = 0;
    __syncthreads();

    int rbeg = b * CAPP;
    int rend = gcur[b << 4];
    // sweep 1: per-node counts (int4)
    for (int e = rbeg + tid * 4; e + 4 <= rend; e += 4096) {
        int4 p4 = *(const int4*)(packed + e);
        if (p4.x != -1) atomicAdd(&cnt[(p4.x >> 20) & (NPB - 1)], 1);
        if (p4.y != -1) atomicAdd(&cnt[(p4.y >> 20) & (NPB - 1)], 1);
        if (p4.z != -1) atomicAdd(&cnt[(p4.z >> 20) & (NPB - 1)], 1);
        if (p4.w != -1) atomicAdd(&cnt[(p4.w >> 20) & (NPB - 1)], 1);
    }
    __syncthreads();
    // single-wave exclusive scan over 256 counters -> loc
    if (tid < 64) {
        int tmp[4];
        int s = 0;
        int base = tid * 4;
        #pragma unroll
        for (int j = 0; j < 4; j++) { tmp[j] = s; s += cnt[base + j]; }
        int incl = s;
        #pragma unroll
        for (int o = 1; o < 64; o <<= 1) {
            int t = __shfl_up(incl, o, 64);
            if (tid >= o) incl += t;
        }
        int excl = incl - s;
        #pragma unroll
        for (int j = 0; j < 4; j++) loc[base + j] = excl + tmp[j];
    }
    __syncthreads();

    // per-node outputs
    int cbase = b * CAP2;
    if (tid < NPB) {
        int node = (b << BSH2) + tid;
        if (node < N) {
            int v = cnt[tid];
            int ep = loc[tid];
            rbc[node] = make_int2(cbase + ep, v);
            float df = (float)v; df = df < 1.0f ? 1.0f : df;
            float r = rsqrtf(df);
            norm[node] = r;
            norm2[node] = r * r;
        }
    }
    __syncthreads();
    // sweep 2: place compacted csr (loc doubles as placement cursor)
    for (int e = rbeg + tid * 4; e + 4 <= rend; e += 4096) {
        int4 p4 = *(const int4*)(packed + e);
        int l, pos;
        if (p4.x != -1) { l = (p4.x >> 20) & (NPB - 1); pos = atomicAdd(&loc[l], 1); csr[cbase + pos] = p4.x & 0xFFFFF; }
        if (p4.y != -1) { l = (p4.y >> 20) & (NPB - 1); pos = atomicAdd(&loc[l], 1); csr[cbase + pos] = p4.y & 0xFFFFF; }
        if (p4.z != -1) { l = (p4.z >> 20) & (NPB - 1); pos = atomicAdd(&loc[l], 1); csr[cbase + pos] = p4.z & 0xFFFFF; }
        if (p4.w != -1) { l = (p4.w >> 20) & (NPB - 1); pos = atomicAdd(&loc[l], 1); csr[cbase + pos] = p4.w & 0xFFFFF; }
    }
}

// ---------------- gather: fp16 rows, 8-lane groups x uint4, unroll-2 ----------------
// One wave per node; group g (8 lanes) handles edges beg+g, beg+g+8, ...
// Each lane loads 16 B (8 halves) -> one wave VMEM instruction covers 8 edges.
template <bool OUTHALF>
__global__ __launch_bounds__(256) void gather_h(const __half* __restrict__ x,
                                                const int2* __restrict__ rbc,
                                                const int* __restrict__ csr,
                                                const float* __restrict__ post,
                                                void* __restrict__ outv, int N) {
    int w = blockIdx.x * 4 + (threadIdx.x >> 6);
    if (w >= N) return;
    int lane = threadIdx.x & 63;
    int g = lane >> 3;
    int sub = lane & 7;
    int2 bc = rbc[w];
    int beg = bc.x, end = bc.x + bc.y;
    const uint4* x16 = (const uint4*)x;   // row = 8 uint4 (128 B)
    float a[8];
    #pragma unroll
    for (int i = 0; i < 8; i++) a[i] = 0.f;
    int e = beg + g;
    for (; e + 8 < end; e += 16) {
        int s0 = csr[e];
        int s1 = csr[e + 8];
        uint4 u0 = x16[s0 * 8 + sub];
        uint4 u1 = x16[s1 * 8 + sub];
        float2 f;
        f = __half22float2(*(const __half2*)&u0.x); a[0] += f.x; a[1] += f.y;
        f = __half22float2(*(const __half2*)&u0.y); a[2] += f.x; a[3] += f.y;
        f = __half22float2(*(const __half2*)&u0.z); a[4] += f.x; a[5] += f.y;
        f = __half22float2(*(const __half2*)&u0.w); a[6] += f.x; a[7] += f.y;
        f = __half22float2(*(const __half2*)&u1.x); a[0] += f.x; a[1] += f.y;
        f = __half22float2(*(const __half2*)&u1.y); a[2] += f.x; a[3] += f.y;
        f = __half22float2(*(const __half2*)&u1.z); a[4] += f.x; a[5] += f.y;
        f = __half22float2(*(const __half2*)&u1.w); a[6] += f.x; a[7] += f.y;
    }
    if (e < end) {
        int s0 = csr[e];
        uint4 u0 = x16[s0 * 8 + sub];
        float2 f;
        f = __half22float2(*(const __half2*)&u0.x); a[0] += f.x; a[1] += f.y;
        f = __half22float2(*(const __half2*)&u0.y); a[2] += f.x; a[3] += f.y;
        f = __half22float2(*(const __half2*)&u0.z); a[4] += f.x; a[5] += f.y;
        f = __half22float2(*(const __half2*)&u0.w); a[6] += f.x; a[7] += f.y;
    }
    #pragma unroll
    for (int i = 0; i < 8; i++) {
        a[i] += __shfl_xor(a[i], 8, 64);
        a[i] += __shfl_xor(a[i], 16, 64);
        a[i] += __shfl_xor(a[i], 32, 64);
    }
    if (g == 0) {
        float pn = post[w];
        #pragma unroll
        for (int i = 0; i < 8; i++) a[i] *= pn;
        if (OUTHALF) {
            __half2 h0 = __floats2half2_rn(a[0], a[1]);
            __half2 h1 = __floats2half2_rn(a[2], a[3]);
            __half2 h2 = __floats2half2_rn(a[4], a[5]);
            __half2 h3 = __floats2half2_rn(a[6], a[7]);
            uint4 u;
            u.x = *(unsigned int*)&h0;
            u.y = *(unsigned int*)&h1;
            u.z = *(unsigned int*)&h2;
            u.w = *(unsigned int*)&h3;
            ((uint4*)outv)[(long)w * 8 + sub] = u;
        } else {
            float4 r0; r0.x = a[0]; r0.y = a[1]; r0.z = a[2]; r0.w = a[3];
            float4 r1; r1.x = a[4]; r1.y = a[5]; r1.z = a[6]; r1.w = a[7];
            ((float4*)outv)[(long)w * 16 + sub * 2]     = r0;
            ((float4*)outv)[(long)w * 16 + sub * 2 + 1] = r1;
        }
    }
}

// ---------------- fallback (atomic push, round-1, pure fp32) ----------------

__global__ void deg_kernel_f(const int* __restrict__ dst, float* __restrict__ deg, int E) {
    int e = blockIdx.x * blockDim.x + threadIdx.x;
    if (e < E) unsafeAtomicAdd(&deg[dst[e]], 1.0f);
}

__global__ void norm_kernel_f(float* __restrict__ deg_norm, float* __restrict__ norm2, int N) {
    int i = blockIdx.x * blockDim.x + threadIdx.x;
    if (i < N) {
        float d = deg_norm[i];
        d = d < 1.0f ? 1.0f : d;
        float r = rsqrtf(d);
        deg_norm[i] = r;
        norm2[i] = r * r;
    }
}

__global__ void scatter_kernel(const float* __restrict__ x,
                               const float* __restrict__ scale,
                               const int* __restrict__ src,
                               const int* __restrict__ dst,
                               float* __restrict__ out, int E) {
    long idx = (long)blockIdx.x * blockDim.x + threadIdx.x;
    int e = (int)(idx >> 6);
    int lane = (int)(idx & 63);
    if (e < E) {
        int s = src[e];
        int d0 = dst[e];
        float v = x[(long)s * D + lane] * scale[s];
        unsafeAtomicAdd(&out[(long)d0 * D + lane], v);
    }
}

__global__ void scale_kernel(float* __restrict__ out, const float* __restrict__ norm, long n) {
    long i = (long)blockIdx.x * blockDim.x + threadIdx.x;
    if (i < n) out[i] *= norm[i >> 6];
}

// ---------------- launch ----------------

extern "C" void kernel_launch(void* const* d_in, const int* in_sizes, int n_in,
                              void* d_out, int out_size, void* d_ws, size_t ws_size,
                              hipStream_t stream) {
    const float* feat = (const float*)d_in[0];
    const int*   src  = (const int*)d_in[1];
    const int*   dst  = (const int*)d_in[2];
    float* out = (float*)d_out;

    const int N = in_sizes[0] / D;   // 100000
    const int E = in_sizes[1];       // 1200000
    const long ND = (long)N * D;
    const int NB2 = (N + NPB - 1) >> BSH2;   // 256-node buckets

    // ws layout (4B elems):
    //   gcur[NB2_MAX*16] | rbc[2N] (int2) | norm[N] | norm2[N] |
    //   csr[NB2*CAP2] | feat16[ND/2] | buf1h[max(ND/2, NB2*CAPP)]
    //   (packed regions alias buf1h -- dead before gather1 writes buf1h)
    long o_gcur = 0;
    long o_rbc  = o_gcur + NB2_MAX * 16;      // even -> int2 aligned
    long o_norm = o_rbc + 2L * N;
    long o_norm2 = o_norm + N;
    long o_csr  = (o_norm2 + N + 3) & ~3L;
    long o_f16  = (o_csr + (long)NB2 * CAP2 + 3) & ~3L;
    long o_buf1 = (o_f16 + ND / 2 + 3) & ~3L;
    long pk_len = (long)NB2 * CAPP;
    long buf1_len = (ND / 2 > pk_len) ? ND / 2 : pk_len;
    size_t need = (size_t)(o_buf1 + buf1_len) * 4;

    if (ws_size >= need && N <= (1 << 20) && NB2 <= NB2_MAX) {
        int*   bi = (int*)d_ws;
        float* bf = (float*)d_ws;
        int* gcur    = bi + o_gcur;
        int2* rbc    = (int2*)(bi + o_rbc);
        float* norm  = bf + o_norm;
        float* norm2 = bf + o_norm2;
        int* csr     = bi + o_csr;
        __half* feat16 = (__half*)(bi + o_f16);
        __half* buf1h  = (__half*)(bi + o_buf1);
        int* packed  = bi + o_buf1;

        int pblocks = (E + PCHUNK - 1) / PCHUNK;

        init_cursors<<<(NB2 + 255) / 256, 256, 0, stream>>>(gcur, NB2);
        partition_direct<<<pblocks, 1024, 0, stream>>>(src, dst, gcur, packed, E, NB2);
        bucket_csr<<<NB2, 1024, 0, stream>>>(packed, gcur, rbc, norm, norm2, csr, N, NB2);
        // feat16 = norm ⊙ feat (fp16)
        long n4 = ND / 4;
        feat_to_half<<<(int)((n4 + 255) / 256), 256, 0, stream>>>(
            (const float4*)feat, norm, (uint2*)feat16, n4);

        int gblocks = (N + 3) / 4;
        // hop 1: buf1h = half( norm2 ⊙ S(feat16) )
        gather_h<true><<<gblocks, 256, 0, stream>>>(feat16, rbc, csr, norm2, buf1h, N);
        // hop 2: out = norm ⊙ S(buf1h)   (fp32)
        gather_h<false><<<gblocks, 256, 0, stream>>>(buf1h, rbc, csr, norm, out, N);
    } else {
        // fallback: atomic push mode (fp32, needs only 2N+ND floats)
        float* norm  = (float*)d_ws;
        float* norm2 = norm + N;
        float* buf1  = norm2 + N;

        long nz = 2L * N + ND;
        zero_f32<<<(int)((nz + 255) / 256), 256, 0, stream>>>((float*)d_ws, nz);
        zero_f32<<<(int)((ND + 255) / 256), 256, 0, stream>>>(out, ND);
        deg_kernel_f<<<(E + 255) / 256, 256, 0, stream>>>(dst, norm, E);
        norm_kernel_f<<<(N + 255) / 256, 256, 0, stream>>>(norm, norm2, N);
        long work = (long)E * D;
        int blocks = (int)((work + 255) / 256);
        scatter_kernel<<<blocks, 256, 0, stream>>>(feat, norm, src, dst, buf1, E);
        scatter_kernel<<<blocks, 256, 0, stream>>>(buf1, norm2, src, dst, out, E);
        scale_kernel<<<(int)((ND + 255) / 256), 256, 0, stream>>>(out, norm, ND);
    }
}